// Round 2
// 932.398 us; speedup vs baseline: 1.0169x; 1.0169x over previous
//
#include <hip/hip_runtime.h>
#include <cstdint>

typedef _Float16 half8  __attribute__((ext_vector_type(8)));
typedef _Float16 half4v __attribute__((ext_vector_type(4)));
typedef float    f32x4  __attribute__((ext_vector_type(4)));

#define MFMA_F16(a,b,c) __builtin_amdgcn_mfma_f32_16x16x32_f16(a,b,c,0,0,0)

static constexpr int D = 1024, H = 16, DK = 64, BATCH = 8, NQ = 1024;
static constexpr int NKP = 1040;  // 1024 real keys + 8 memory slots + 8 pad

// Async global->LDS, 16B per lane. LDS dest is wave-uniform base + lane*16.
__device__ __forceinline__ void async_copy16(_Float16* lds, const _Float16* g) {
  __builtin_amdgcn_global_load_lds(
      (const __attribute__((address_space(1))) void*)g,
      (__attribute__((address_space(3))) void*)lds, 16, 0, 0);
}

// ---------------------------------------------------------------------------
// One-shot fp32 -> fp16 convert of activations + weights (8 elems/thread).
// ---------------------------------------------------------------------------
__global__ __launch_bounds__(256) void convert_all(
    const float* __restrict__ q, const float* __restrict__ k, const float* __restrict__ v,
    const float* __restrict__ w_in, const float* __restrict__ w_out,
    _Float16* __restrict__ q16, _Float16* __restrict__ k16, _Float16* __restrict__ v16,
    _Float16* __restrict__ win16, _Float16* __restrict__ wout16)
{
  const unsigned NA = 8192u * 1024u;
  const unsigned NW = 3u * 1024u * 1024u;
  unsigned idx = blockIdx.x * 256u + threadIdx.x;
  unsigned e = idx * 8u;
  const float* src;
  _Float16* dst;
  unsigned off;
  if (e < NA)            { src = q;     dst = q16;    off = e; }
  else if (e < 2 * NA)   { src = k;     dst = k16;    off = e - NA; }
  else if (e < 3 * NA)   { src = v;     dst = v16;    off = e - 2 * NA; }
  else if (e < 3 * NA + NW) { src = w_in; dst = win16; off = e - 3 * NA; }
  else                   { src = w_out; dst = wout16; off = e - 3 * NA - NW; }
  float4 f0 = ((const float4*)(src + off))[0];
  float4 f1 = ((const float4*)(src + off))[1];
  half8 h;
  h[0]=(_Float16)f0.x; h[1]=(_Float16)f0.y; h[2]=(_Float16)f0.z; h[3]=(_Float16)f0.w;
  h[4]=(_Float16)f1.x; h[5]=(_Float16)f1.y; h[6]=(_Float16)f1.z; h[7]=(_Float16)f1.w;
  *(half8*)(dst + off) = h;
}

// ---------------------------------------------------------------------------
// QKV projection, BK=64, XOR-swizzled staging (linear LDS dest +
// pre-swizzled global source + swizzled ds_read -> conflict-free b128 reads).
// ---------------------------------------------------------------------------
__global__ __launch_bounds__(256) void gemm_qkv(
    const _Float16* __restrict__ A16,  // 3 segments of 8192x1024, z-indexed
    const _Float16* __restrict__ W16,  // 3072x1024
    const float* __restrict__ bias,
    _Float16* __restrict__ Qo, _Float16* __restrict__ Ko, _Float16* __restrict__ Vo)
{
  const int z = blockIdx.z;
  const _Float16* __restrict__ A = A16 + (size_t)z * 8192 * 1024;
  const _Float16* __restrict__ Wz = W16 + (size_t)z * D * D;
  const int row0 = blockIdx.x * 128;
  const int col0 = blockIdx.y * 128;

  __shared__ _Float16 As[128 * 64];
  __shared__ _Float16 Bs[128 * 64];

  const int tid = threadIdx.x;
  const int wv = tid >> 6, lane = tid & 63, c = lane & 15, g = lane >> 4;
  const int ar0 = (wv & 1) * 64, bc0 = (wv >> 1) * 64;
  const int cswz = (c & 7) << 3;

  // staging: call u covers rows [32u,32u+32); thread -> (row = 32u + tid>>3,
  // swizzled col8). LDS dest stays linear: base + lane*16B.
  const int srow = tid >> 3;
  const int sk8 = (((tid & 7) ^ ((tid >> 3) & 7)) << 3);
  const _Float16* ag = A + (size_t)(row0 + srow) * D + sk8;
  const _Float16* bg = Wz + (size_t)(col0 + srow) * D + sk8;
  _Float16* al = &As[512 * wv];
  _Float16* bl = &Bs[512 * wv];

  f32x4 acc[4][4];
#pragma unroll
  for (int i = 0; i < 4; i++)
#pragma unroll
    for (int j = 0; j < 4; j++) acc[i][j] = (f32x4)(0.f);

  for (int kb = 0; kb < D; kb += 64) {
#pragma unroll
    for (int u = 0; u < 4; u++) {
      async_copy16(al + 2048 * u, ag + kb + (size_t)(32 * u) * D);
      async_copy16(bl + 2048 * u, bg + kb + (size_t)(32 * u) * D);
    }
    __syncthreads();
#pragma unroll
    for (int kk = 0; kk < 2; kk++) {
      half8 af[4], bf[4];
#pragma unroll
      for (int i = 0; i < 4; i++)
        af[i] = *(const half8*)&As[(ar0 + 16 * i + c) * 64 + ((32 * kk + 8 * g) ^ cswz)];
#pragma unroll
      for (int j = 0; j < 4; j++)
        bf[j] = *(const half8*)&Bs[(bc0 + 16 * j + c) * 64 + ((32 * kk + 8 * g) ^ cswz)];
#pragma unroll
      for (int i = 0; i < 4; i++)
#pragma unroll
        for (int j = 0; j < 4; j++) acc[i][j] = MFMA_F16(af[i], bf[j], acc[i][j]);
    }
    __syncthreads();
  }

#pragma unroll
  for (int j = 0; j < 4; j++) {
    int n = col0 + bc0 + 16 * j + c;
    float bb = (float)(_Float16)bias[z * D + n];   // reference casts bias to fp16
    int h_ = n >> 6, dk = n & 63;
#pragma unroll
    for (int i = 0; i < 4; i++) {
#pragma unroll
      for (int r = 0; r < 4; r++) {
        int m = row0 + ar0 + 16 * i + 4 * g + r;
        int b = m & 7, nq = m >> 3;
        float val = acc[i][j][r] + bb;
        if (z == 0)
          Qo[(((size_t)b * H + h_) * NQ + nq) * DK + dk] = (_Float16)(val * 0.125f);
        else if (z == 1)
          Ko[(((size_t)b * H + h_) * NKP + nq) * DK + dk] = (_Float16)val;
        else
          Vo[(((size_t)b * H + h_) * NKP + nq) * DK + dk] = (_Float16)val;
      }
    }
  }
}

// ---------------------------------------------------------------------------
// Memory slots: K rows 1024..1031 = 32*m_k, V rows = sqrt(8)*m_v; 1032..1039 = 0.
// ---------------------------------------------------------------------------
__global__ __launch_bounds__(256) void fill_slots(
    const float* __restrict__ mk, const float* __restrict__ mv,
    _Float16* __restrict__ Ko, _Float16* __restrict__ Vo)
{
  int idx = blockIdx.x * 256 + threadIdx.x;   // 262144 total
  int which = idx >> 17;
  int e = idx & 131071;
  int dk = e & 63, r = (e >> 6) & 15, h = (e >> 10) & 15, b = (e >> 14) & 7;
  float val = 0.f;
  if (r < 8) {
    int src = r * D + h * DK + dk;
    val = which ? 2.8284271247461903f * mv[src] : 32.f * mk[src];
  }
  _Float16* dst = which ? Vo : Ko;
  dst[(((size_t)b * H + h) * NKP + 1024 + r) * DK + dk] = (_Float16)val;
}

// ---------------------------------------------------------------------------
// Fused attention: 8 waves, Q-tile = 128 rows per block (2x staging
// amortization vs 64). Qs/Ps share one LDS buffer (Q consumed into regs
// before first loop barrier; Ps rows are wave-private).
// ---------------------------------------------------------------------------
__global__ __launch_bounds__(512) void attn(
    const _Float16* __restrict__ Qg, const _Float16* __restrict__ Kg,
    const _Float16* __restrict__ Vg, const float* __restrict__ mask,
    _Float16* __restrict__ Hid)
{
  const int qt = blockIdx.x;        // 0..7 (128 q-rows each)
  const int bh = blockIdx.y;        // 0..127 == b*16+h
  const int b = bh >> 4, h = bh & 15;
  const int tid = threadIdx.x;
  const int wv = tid >> 6, lane = tid & 63, c = lane & 15, g = lane >> 4;

  __shared__ _Float16 QPs[128 * 72];  // Q staging, then P[q][key] (wave-private rows)
  __shared__ _Float16 Ks[64 * 72];
  __shared__ _Float16 Vt[64 * 72];    // transposed: [dv][key]

  const _Float16* qbase = Qg + ((size_t)bh * NQ + qt * 128) * DK;
#pragma unroll
  for (int u = 0; u < 2; u++) {
    int id = tid + 512 * u;
    int row = id >> 3, m8 = (id & 7) * 8;
    *(int4*)&QPs[row * 72 + m8] = *(const int4*)(qbase + row * DK + m8);
  }
  __syncthreads();
  const int qrow = (wv * 16 + c) * 72;
  half8 qf0 = *(const half8*)&QPs[qrow + 8 * g];
  half8 qf1 = *(const half8*)&QPs[qrow + 32 + 8 * g];

  f32x4 oacc[4];
#pragma unroll
  for (int j = 0; j < 4; j++) oacc[j] = (f32x4)(0.f);
  float lpart = 0.f;

  const float* maskbase = mask + ((size_t)bh << 20) + ((size_t)(qt * 128 + wv * 16 + c) << 10);
  const _Float16* kbase_g = Kg + (size_t)bh * NKP * DK;
  const _Float16* vbase_g = Vg + (size_t)bh * NKP * DK;

  for (int ci = 0; ci < 17; ++ci) {
    const int kb = ci * 64;
    const int nk = (ci < 16) ? 64 : 16;
    __syncthreads();   // prior chunk's MFMA reads of Ks/Vt are done

    f32x4 sinit[4];
    if (ci < 16) {
#pragma unroll
      for (int t = 0; t < 4; t++)
        sinit[t] = *(const f32x4*)(maskbase + kb + 16 * t + 4 * g);
    } else {
      float iv = (g < 2) ? 0.f : -1e30f;   // keys >= 1032 masked out
      sinit[0] = (f32x4){iv, iv, iv, iv};
    }

    // stage K chunk (row-major, padded): 512 threads cover 64 rows x 64
    {
      int row = tid >> 3, m8 = (tid & 7) * 8;
      if (row < nk)
        *(int4*)&Ks[row * 72 + m8] = *(const int4*)(kbase_g + (size_t)(kb + row) * DK + m8);
    }
    // stage V transposed: threads 0..255 handle a key-pair x 8-dv block
    if (tid < 256) {
      int kp = tid & 31, dvo = (tid >> 5) * 8;
      if (2 * kp < nk) {
        uint4 a4 = *(const uint4*)(vbase_g + (size_t)(kb + 2 * kp) * DK + dvo);
        uint4 b4 = *(const uint4*)(vbase_g + (size_t)(kb + 2 * kp + 1) * DK + dvo);
        uint32_t aw[4] = {a4.x, a4.y, a4.z, a4.w};
        uint32_t bw[4] = {b4.x, b4.y, b4.z, b4.w};
#pragma unroll
        for (int w = 0; w < 4; w++) {
          uint32_t lo = (aw[w] & 0xffffu) | (bw[w] << 16);
          uint32_t hi = (aw[w] >> 16) | (bw[w] & 0xffff0000u);
          *(uint32_t*)&Vt[(dvo + 2 * w) * 72 + 2 * kp] = lo;
          *(uint32_t*)&Vt[(dvo + 2 * w + 1) * 72 + 2 * kp] = hi;
        }
      } else if (nk == 16) {
        // zero-pad keys [16,64) so stale LDS can't poison PV
#pragma unroll
        for (int w = 0; w < 4; w++) {
          *(uint32_t*)&Vt[(dvo + 2 * w) * 72 + 2 * kp] = 0u;
          *(uint32_t*)&Vt[(dvo + 2 * w + 1) * 72 + 2 * kp] = 0u;
        }
      }
    }
    __syncthreads();

    const int ntile = nk >> 4;
    for (int t = 0; t < ntile; ++t) {
      f32x4 s = sinit[t];
      half8 kf0 = *(const half8*)&Ks[(16 * t + c) * 72 + 8 * g];
      half8 kf1 = *(const half8*)&Ks[(16 * t + c) * 72 + 32 + 8 * g];
      s = MFMA_F16(kf0, qf0, s);
      s = MFMA_F16(kf1, qf1, s);
      f32x4 p;
      p[0] = __expf(s[0]); p[1] = __expf(s[1]); p[2] = __expf(s[2]); p[3] = __expf(s[3]);
      lpart += p[0] + p[1] + p[2] + p[3];
      half4v ph;
      ph[0] = (_Float16)p[0]; ph[1] = (_Float16)p[1];
      ph[2] = (_Float16)p[2]; ph[3] = (_Float16)p[3];
      *(half4v*)&QPs[qrow + 16 * t + 4 * g] = ph;   // P[q][key], 4 consecutive keys
    }
    if (nk == 16) {
      half4v zz = {(_Float16)0, (_Float16)0, (_Float16)0, (_Float16)0};
      *(half4v*)&QPs[qrow + 16 + 4 * g] = zz;       // zero keys 16..31
    }

    const int khalf = (nk == 64) ? 2 : 1;
    for (int kh = 0; kh < khalf; ++kh) {
      half8 pf = *(const half8*)&QPs[qrow + 32 * kh + 8 * g];
#pragma unroll
      for (int j = 0; j < 4; j++) {
        half8 vf = *(const half8*)&Vt[(16 * j + c) * 72 + 32 * kh + 8 * g];
        oacc[j] = MFMA_F16(pf, vf, oacc[j]);
      }
    }
  }

  // finalize: row sums of exp live per-column(q=c); reduce over g groups
  lpart += __shfl_xor(lpart, 16);
  lpart += __shfl_xor(lpart, 32);
  float inv_[4];
#pragma unroll
  for (int r = 0; r < 4; r++) {
    float lq = __shfl(lpart, 4 * g + r);   // lane with c == 4g+r holds l for that q row
    inv_[r] = __builtin_amdgcn_rcpf(lq);
  }
#pragma unroll
  for (int j = 0; j < 4; j++) {
    int col = h * DK + 16 * j + c;
#pragma unroll
    for (int r = 0; r < 4; r++) {
      int q = qt * 128 + wv * 16 + 4 * g + r;
      Hid[((size_t)q * BATCH + b) * D + col] = (_Float16)(oacc[j][r] * inv_[r]);
    }
  }
}

// ---------------------------------------------------------------------------
// Output projection, same BK=64 swizzled structure; fp32 out.
// ---------------------------------------------------------------------------
__global__ __launch_bounds__(256) void gemm_out(
    const _Float16* __restrict__ Ah, const _Float16* __restrict__ W16,
    const float* __restrict__ bias, float* __restrict__ Out)
{
  const int row0 = blockIdx.x * 128, col0 = blockIdx.y * 128;
  __shared__ _Float16 As[128 * 64];
  __shared__ _Float16 Bs[128 * 64];
  const int tid = threadIdx.x;
  const int wv = tid >> 6, lane = tid & 63, c = lane & 15, g = lane >> 4;
  const int ar0 = (wv & 1) * 64, bc0 = (wv >> 1) * 64;
  const int cswz = (c & 7) << 3;

  const int srow = tid >> 3;
  const int sk8 = (((tid & 7) ^ ((tid >> 3) & 7)) << 3);
  const _Float16* ag = Ah + (size_t)(row0 + srow) * D + sk8;
  const _Float16* bg = W16 + (size_t)(col0 + srow) * D + sk8;
  _Float16* al = &As[512 * wv];
  _Float16* bl = &Bs[512 * wv];

  f32x4 acc[4][4];
#pragma unroll
  for (int i = 0; i < 4; i++)
#pragma unroll
    for (int j = 0; j < 4; j++) acc[i][j] = (f32x4)(0.f);

  for (int kb = 0; kb < D; kb += 64) {
#pragma unroll
    for (int u = 0; u < 4; u++) {
      async_copy16(al + 2048 * u, ag + kb + (size_t)(32 * u) * D);
      async_copy16(bl + 2048 * u, bg + kb + (size_t)(32 * u) * D);
    }
    __syncthreads();
#pragma unroll
    for (int kk = 0; kk < 2; kk++) {
      half8 af[4], bf[4];
#pragma unroll
      for (int i = 0; i < 4; i++)
        af[i] = *(const half8*)&As[(ar0 + 16 * i + c) * 64 + ((32 * kk + 8 * g) ^ cswz)];
#pragma unroll
      for (int j = 0; j < 4; j++)
        bf[j] = *(const half8*)&Bs[(bc0 + 16 * j + c) * 64 + ((32 * kk + 8 * g) ^ cswz)];
#pragma unroll
      for (int i = 0; i < 4; i++)
#pragma unroll
        for (int j = 0; j < 4; j++) acc[i][j] = MFMA_F16(af[i], bf[j], acc[i][j]);
    }
    __syncthreads();
  }

#pragma unroll
  for (int j = 0; j < 4; j++) {
    int n = col0 + bc0 + 16 * j + c;
    float bb = bias[n];   // out_b stays fp32 in the reference
#pragma unroll
    for (int i = 0; i < 4; i++) {
#pragma unroll
      for (int r = 0; r < 4; r++) {
        int m = row0 + ar0 + 16 * i + 4 * g + r;
        Out[(size_t)m * D + n] = acc[i][j][r] + bb;
      }
    }
  }
}

// ---------------------------------------------------------------------------
extern "C" void kernel_launch(void* const* d_in, const int* in_sizes, int n_in,
                              void* d_out, int out_size, void* d_ws, size_t ws_size,
                              hipStream_t stream) {
  const float* queries   = (const float*)d_in[0];
  const float* keys      = (const float*)d_in[1];
  const float* values    = (const float*)d_in[2];
  const float* m_k       = (const float*)d_in[3];
  const float* m_v       = (const float*)d_in[4];
  const float* attn_mask = (const float*)d_in[5];
  const float* in_proj_w = (const float*)d_in[6];
  const float* in_proj_b = (const float*)d_in[7];
  const float* out_w     = (const float*)d_in[8];
  const float* out_b     = (const float*)d_in[9];
  float* out = (float*)d_out;

  const size_t NA = (size_t)8192 * 1024;
  _Float16* A16  = (_Float16*)d_ws;            // 3*NA  (q16,k16,v16 contiguous)
  _Float16* Win16  = A16 + 3 * NA;             // 3*1024*1024
  _Float16* Wout16 = Win16 + (size_t)3 * 1024 * 1024;  // 1024*1024
  _Float16* Qw = Wout16 + (size_t)1024 * 1024;          // 8*16*1024*64
  _Float16* Kw = Qw + (size_t)8 * 16 * 1024 * 64;       // 8*16*1040*64
  _Float16* Vw = Kw + (size_t)8 * 16 * 1040 * 64;       // 8*16*1040*64
  _Float16* Hw = Vw + (size_t)8 * 16 * 1040 * 64;       // 8192*1024

  hipLaunchKernelGGL(convert_all, dim3(14336), dim3(256), 0, stream,
                     queries, keys, values, in_proj_w, out_w,
                     A16, A16 + NA, A16 + 2 * NA, Win16, Wout16);
  hipLaunchKernelGGL(gemm_qkv, dim3(64, 8, 3), dim3(256), 0, stream,
                     A16, Win16, in_proj_b, Qw, Kw, Vw);
  hipLaunchKernelGGL(fill_slots, dim3(1024), dim3(256), 0, stream, m_k, m_v, Kw, Vw);
  hipLaunchKernelGGL(attn, dim3(8, 128), dim3(512), 0, stream, Qw, Kw, Vw, attn_mask, Hw);
  hipLaunchKernelGGL(gemm_out, dim3(64, 8), dim3(256), 0, stream, Hw, Wout16, out_b, out);
}

// Round 3
// 914.766 us; speedup vs baseline: 1.0365x; 1.0193x over previous
//
#include <hip/hip_runtime.h>
#include <cstdint>

typedef _Float16 half8  __attribute__((ext_vector_type(8)));
typedef _Float16 half4v __attribute__((ext_vector_type(4)));
typedef float    f32x4  __attribute__((ext_vector_type(4)));

#define MFMA_F16(a,b,c) __builtin_amdgcn_mfma_f32_16x16x32_f16(a,b,c,0,0,0)

static constexpr int D = 1024, H = 16, DK = 64, BATCH = 8, NQ = 1024;
static constexpr int NKP = 1040;  // 1024 real keys + 8 memory slots + 8 pad

// Async global->LDS, 16B per lane. LDS dest is wave-uniform base + lane*16.
__device__ __forceinline__ void async_copy16(_Float16* lds, const _Float16* g) {
  __builtin_amdgcn_global_load_lds(
      (const __attribute__((address_space(1))) void*)g,
      (__attribute__((address_space(3))) void*)lds, 16, 0, 0);
}

// ---------------------------------------------------------------------------
// One-shot fp32 -> fp16 convert of activations + weights (8 elems/thread).
// ---------------------------------------------------------------------------
__global__ __launch_bounds__(256) void convert_all(
    const float* __restrict__ q, const float* __restrict__ k, const float* __restrict__ v,
    const float* __restrict__ w_in, const float* __restrict__ w_out,
    _Float16* __restrict__ q16, _Float16* __restrict__ k16, _Float16* __restrict__ v16,
    _Float16* __restrict__ win16, _Float16* __restrict__ wout16)
{
  const unsigned NA = 8192u * 1024u;
  const unsigned NW = 3u * 1024u * 1024u;
  unsigned idx = blockIdx.x * 256u + threadIdx.x;
  unsigned e = idx * 8u;
  const float* src;
  _Float16* dst;
  unsigned off;
  if (e < NA)            { src = q;     dst = q16;    off = e; }
  else if (e < 2 * NA)   { src = k;     dst = k16;    off = e - NA; }
  else if (e < 3 * NA)   { src = v;     dst = v16;    off = e - 2 * NA; }
  else if (e < 3 * NA + NW) { src = w_in; dst = win16; off = e - 3 * NA; }
  else                   { src = w_out; dst = wout16; off = e - 3 * NA - NW; }
  float4 f0 = ((const float4*)(src + off))[0];
  float4 f1 = ((const float4*)(src + off))[1];
  half8 h;
  h[0]=(_Float16)f0.x; h[1]=(_Float16)f0.y; h[2]=(_Float16)f0.z; h[3]=(_Float16)f0.w;
  h[4]=(_Float16)f1.x; h[5]=(_Float16)f1.y; h[6]=(_Float16)f1.z; h[7]=(_Float16)f1.w;
  *(half8*)(dst + off) = h;
}

// ---------------------------------------------------------------------------
// QKV projection, BK=64, XOR-swizzled staging (linear LDS dest +
// pre-swizzled global source + swizzled ds_read -> conflict-free b128 reads).
// ---------------------------------------------------------------------------
__global__ __launch_bounds__(256) void gemm_qkv(
    const _Float16* __restrict__ A16,  // 3 segments of 8192x1024, z-indexed
    const _Float16* __restrict__ W16,  // 3072x1024
    const float* __restrict__ bias,
    _Float16* __restrict__ Qo, _Float16* __restrict__ Ko, _Float16* __restrict__ Vo)
{
  const int z = blockIdx.z;
  const _Float16* __restrict__ A = A16 + (size_t)z * 8192 * 1024;
  const _Float16* __restrict__ Wz = W16 + (size_t)z * D * D;
  const int row0 = blockIdx.x * 128;
  const int col0 = blockIdx.y * 128;

  __shared__ _Float16 As[128 * 64];
  __shared__ _Float16 Bs[128 * 64];

  const int tid = threadIdx.x;
  const int wv = tid >> 6, lane = tid & 63, c = lane & 15, g = lane >> 4;
  const int ar0 = (wv & 1) * 64, bc0 = (wv >> 1) * 64;
  const int cswz = (c & 7) << 3;

  const int srow = tid >> 3;
  const int sk8 = (((tid & 7) ^ ((tid >> 3) & 7)) << 3);
  const _Float16* ag = A + (size_t)(row0 + srow) * D + sk8;
  const _Float16* bg = Wz + (size_t)(col0 + srow) * D + sk8;
  _Float16* al = &As[512 * wv];
  _Float16* bl = &Bs[512 * wv];

  f32x4 acc[4][4];
#pragma unroll
  for (int i = 0; i < 4; i++)
#pragma unroll
    for (int j = 0; j < 4; j++) acc[i][j] = (f32x4)(0.f);

  for (int kb = 0; kb < D; kb += 64) {
#pragma unroll
    for (int u = 0; u < 4; u++) {
      async_copy16(al + 2048 * u, ag + kb + (size_t)(32 * u) * D);
      async_copy16(bl + 2048 * u, bg + kb + (size_t)(32 * u) * D);
    }
    __syncthreads();
#pragma unroll
    for (int kk = 0; kk < 2; kk++) {
      half8 af[4], bf[4];
#pragma unroll
      for (int i = 0; i < 4; i++)
        af[i] = *(const half8*)&As[(ar0 + 16 * i + c) * 64 + ((32 * kk + 8 * g) ^ cswz)];
#pragma unroll
      for (int j = 0; j < 4; j++)
        bf[j] = *(const half8*)&Bs[(bc0 + 16 * j + c) * 64 + ((32 * kk + 8 * g) ^ cswz)];
#pragma unroll
      for (int i = 0; i < 4; i++)
#pragma unroll
        for (int j = 0; j < 4; j++) acc[i][j] = MFMA_F16(af[i], bf[j], acc[i][j]);
    }
    __syncthreads();
  }

#pragma unroll
  for (int j = 0; j < 4; j++) {
    int n = col0 + bc0 + 16 * j + c;
    float bb = (float)(_Float16)bias[z * D + n];   // reference casts bias to fp16
    int h_ = n >> 6, dk = n & 63;
#pragma unroll
    for (int i = 0; i < 4; i++) {
#pragma unroll
      for (int r = 0; r < 4; r++) {
        int m = row0 + ar0 + 16 * i + 4 * g + r;
        int b = m & 7, nq = m >> 3;
        float val = acc[i][j][r] + bb;
        if (z == 0)
          Qo[(((size_t)b * H + h_) * NQ + nq) * DK + dk] = (_Float16)(val * 0.125f);
        else if (z == 1)
          Ko[(((size_t)b * H + h_) * NKP + nq) * DK + dk] = (_Float16)val;
        else
          Vo[(((size_t)b * H + h_) * NKP + nq) * DK + dk] = (_Float16)val;
      }
    }
  }
}

// ---------------------------------------------------------------------------
// Memory slots: K rows 1024..1031 = 32*m_k, V rows = sqrt(8)*m_v; 1032..1039 = 0.
// ---------------------------------------------------------------------------
__global__ __launch_bounds__(256) void fill_slots(
    const float* __restrict__ mk, const float* __restrict__ mv,
    _Float16* __restrict__ Ko, _Float16* __restrict__ Vo)
{
  int idx = blockIdx.x * 256 + threadIdx.x;   // 262144 total
  int which = idx >> 17;
  int e = idx & 131071;
  int dk = e & 63, r = (e >> 6) & 15, h = (e >> 10) & 15, b = (e >> 14) & 7;
  float val = 0.f;
  if (r < 8) {
    int src = r * D + h * DK + dk;
    val = which ? 2.8284271247461903f * mv[src] : 32.f * mk[src];
  }
  _Float16* dst = which ? Vo : Ko;
  dst[(((size_t)b * H + h) * NKP + 1024 + r) * DK + dk] = (_Float16)val;
}

// ---------------------------------------------------------------------------
// Fused attention, 8 waves, Q-tile 128, T14 async-STAGE pipeline:
// chunk ci+1's K/V/mask global loads are issued before chunk ci's compute
// (held in regs across the phase), written to LDS after the next barrier.
// ---------------------------------------------------------------------------
__global__ __launch_bounds__(512) void attn(
    const _Float16* __restrict__ Qg, const _Float16* __restrict__ Kg,
    const _Float16* __restrict__ Vg, const float* __restrict__ mask,
    _Float16* __restrict__ Hid)
{
  const int qt = blockIdx.x;        // 0..7 (128 q-rows each)
  const int bh = blockIdx.y;        // 0..127 == b*16+h
  const int b = bh >> 4, h = bh & 15;
  const int tid = threadIdx.x;
  const int wv = tid >> 6, lane = tid & 63, c = lane & 15, g = lane >> 4;

  __shared__ _Float16 QPs[128 * 72];  // Q staging, then P[q][key] (wave-private rows)
  __shared__ _Float16 Ks[64 * 72];
  __shared__ _Float16 Vt[64 * 72];    // transposed: [dv][key]

  const _Float16* qbase = Qg + ((size_t)bh * NQ + qt * 128) * DK;
  const float* maskbase = mask + ((size_t)bh << 20) + ((size_t)(qt * 128 + wv * 16 + c) << 10);
  const _Float16* kbase_g = Kg + (size_t)bh * NKP * DK;
  const _Float16* vbase_g = Vg + (size_t)bh * NKP * DK;

  // staging roles
  const int krow = tid >> 3;            // 0..63, one int4 (8 halfs) each
  const int km8  = (tid & 7) * 8;
  const int vkp  = tid & 31;            // threads < 256 stage V (key-pair x 8 dv)
  const int vdvo = (tid >> 5) * 8;

  // ---- issue chunk-0 loads (global -> reg), overlap with Q staging ----
  int4 kreg = *(const int4*)(kbase_g + (size_t)krow * DK + km8);
  uint4 va, vb;
  if (tid < 256) {
    va = *(const uint4*)(vbase_g + (size_t)(2 * vkp) * DK + vdvo);
    vb = *(const uint4*)(vbase_g + (size_t)(2 * vkp + 1) * DK + vdvo);
  }
  f32x4 sinit[4];
#pragma unroll
  for (int t = 0; t < 4; t++)
    sinit[t] = *(const f32x4*)(maskbase + 16 * t + 4 * g);

  // ---- Q staging ----
#pragma unroll
  for (int u = 0; u < 2; u++) {
    int id = tid + 512 * u;
    int row = id >> 3, m8 = (id & 7) * 8;
    *(int4*)&QPs[row * 72 + m8] = *(const int4*)(qbase + row * DK + m8);
  }
  __syncthreads();
  const int qrow = (wv * 16 + c) * 72;
  half8 qf0 = *(const half8*)&QPs[qrow + 8 * g];
  half8 qf1 = *(const half8*)&QPs[qrow + 32 + 8 * g];

  f32x4 oacc[4];
#pragma unroll
  for (int j = 0; j < 4; j++) oacc[j] = (f32x4)(0.f);
  float lpart = 0.f;

  for (int ci = 0; ci < 17; ++ci) {
    const int nk = (ci < 16) ? 64 : 16;
    __syncthreads();   // prior chunk's MFMA reads of Ks/Vt are done

    // ---- write phase: chunk ci regs -> LDS ----
    if (krow < nk)
      *(int4*)&Ks[krow * 72 + km8] = kreg;
    if (tid < 256) {
      if (2 * vkp < nk) {
        uint32_t aw[4] = {va.x, va.y, va.z, va.w};
        uint32_t bw[4] = {vb.x, vb.y, vb.z, vb.w};
#pragma unroll
        for (int w = 0; w < 4; w++) {
          uint32_t lo = (aw[w] & 0xffffu) | (bw[w] << 16);
          uint32_t hi = (aw[w] >> 16) | (bw[w] & 0xffff0000u);
          *(uint32_t*)&Vt[(vdvo + 2 * w) * 72 + 2 * vkp] = lo;
          *(uint32_t*)&Vt[(vdvo + 2 * w + 1) * 72 + 2 * vkp] = hi;
        }
      } else if (nk == 16) {
        // zero-pad keys [16,64) so stale LDS can't poison PV
#pragma unroll
        for (int w = 0; w < 4; w++) {
          *(uint32_t*)&Vt[(vdvo + 2 * w) * 72 + 2 * vkp] = 0u;
          *(uint32_t*)&Vt[(vdvo + 2 * w + 1) * 72 + 2 * vkp] = 0u;
        }
      }
    }
    __syncthreads();   // staging visible

    // stash current mask/accumulator init, then issue chunk ci+1 loads
    f32x4 scur[4];
    scur[0] = sinit[0]; scur[1] = sinit[1]; scur[2] = sinit[2]; scur[3] = sinit[3];
    if (ci < 16) {
      const int kbn = (ci + 1) * 64;
      const int nkn = (ci + 1 < 16) ? 64 : 16;
      if (krow < nkn)
        kreg = *(const int4*)(kbase_g + (size_t)(kbn + krow) * DK + km8);
      if (tid < 256 && 2 * vkp < nkn) {
        va = *(const uint4*)(vbase_g + (size_t)(kbn + 2 * vkp) * DK + vdvo);
        vb = *(const uint4*)(vbase_g + (size_t)(kbn + 2 * vkp + 1) * DK + vdvo);
      }
      if (ci + 1 < 16) {
#pragma unroll
        for (int t = 0; t < 4; t++)
          sinit[t] = *(const f32x4*)(maskbase + kbn + 16 * t + 4 * g);
      } else {
        float iv = (g < 2) ? 0.f : -1e30f;   // keys >= 1032 masked out
        sinit[0] = (f32x4){iv, iv, iv, iv};
      }
    }

    // ---- compute chunk ci ----
    const int ntile = nk >> 4;
    for (int t = 0; t < ntile; ++t) {
      f32x4 s = scur[t];
      half8 kf0 = *(const half8*)&Ks[(16 * t + c) * 72 + 8 * g];
      half8 kf1 = *(const half8*)&Ks[(16 * t + c) * 72 + 32 + 8 * g];
      __builtin_amdgcn_s_setprio(1);
      s = MFMA_F16(kf0, qf0, s);
      s = MFMA_F16(kf1, qf1, s);
      __builtin_amdgcn_s_setprio(0);
      f32x4 p;
      p[0] = __expf(s[0]); p[1] = __expf(s[1]); p[2] = __expf(s[2]); p[3] = __expf(s[3]);
      lpart += p[0] + p[1] + p[2] + p[3];
      half4v ph;
      ph[0] = (_Float16)p[0]; ph[1] = (_Float16)p[1];
      ph[2] = (_Float16)p[2]; ph[3] = (_Float16)p[3];
      *(half4v*)&QPs[qrow + 16 * t + 4 * g] = ph;   // P[q][key], 4 consecutive keys
    }
    if (nk == 16) {
      half4v zz = {(_Float16)0, (_Float16)0, (_Float16)0, (_Float16)0};
      *(half4v*)&QPs[qrow + 16 + 4 * g] = zz;       // zero keys 16..31
    }

    const int khalf = (nk == 64) ? 2 : 1;
    for (int kh = 0; kh < khalf; ++kh) {
      half8 pf = *(const half8*)&QPs[qrow + 32 * kh + 8 * g];
      __builtin_amdgcn_s_setprio(1);
#pragma unroll
      for (int j = 0; j < 4; j++) {
        half8 vf = *(const half8*)&Vt[(16 * j + c) * 72 + 32 * kh + 8 * g];
        oacc[j] = MFMA_F16(pf, vf, oacc[j]);
      }
      __builtin_amdgcn_s_setprio(0);
    }
  }

  // finalize: row sums of exp live per-column(q=c); reduce over g groups
  lpart += __shfl_xor(lpart, 16);
  lpart += __shfl_xor(lpart, 32);
  float inv_[4];
#pragma unroll
  for (int r = 0; r < 4; r++) {
    float lq = __shfl(lpart, 4 * g + r);   // lane with c == 4g+r holds l for that q row
    inv_[r] = __builtin_amdgcn_rcpf(lq);
  }
#pragma unroll
  for (int j = 0; j < 4; j++) {
    int col = h * DK + 16 * j + c;
#pragma unroll
    for (int r = 0; r < 4; r++) {
      int q = qt * 128 + wv * 16 + 4 * g + r;
      Hid[((size_t)q * BATCH + b) * D + col] = (_Float16)(oacc[j][r] * inv_[r]);
    }
  }
}

// ---------------------------------------------------------------------------
// Output projection, same BK=64 swizzled structure; fp32 out.
// ---------------------------------------------------------------------------
__global__ __launch_bounds__(256) void gemm_out(
    const _Float16* __restrict__ Ah, const _Float16* __restrict__ W16,
    const float* __restrict__ bias, float* __restrict__ Out)
{
  const int row0 = blockIdx.x * 128, col0 = blockIdx.y * 128;
  __shared__ _Float16 As[128 * 64];
  __shared__ _Float16 Bs[128 * 64];
  const int tid = threadIdx.x;
  const int wv = tid >> 6, lane = tid & 63, c = lane & 15, g = lane >> 4;
  const int ar0 = (wv & 1) * 64, bc0 = (wv >> 1) * 64;
  const int cswz = (c & 7) << 3;

  const int srow = tid >> 3;
  const int sk8 = (((tid & 7) ^ ((tid >> 3) & 7)) << 3);
  const _Float16* ag = Ah + (size_t)(row0 + srow) * D + sk8;
  const _Float16* bg = W16 + (size_t)(col0 + srow) * D + sk8;
  _Float16* al = &As[512 * wv];
  _Float16* bl = &Bs[512 * wv];

  f32x4 acc[4][4];
#pragma unroll
  for (int i = 0; i < 4; i++)
#pragma unroll
    for (int j = 0; j < 4; j++) acc[i][j] = (f32x4)(0.f);

  for (int kb = 0; kb < D; kb += 64) {
#pragma unroll
    for (int u = 0; u < 4; u++) {
      async_copy16(al + 2048 * u, ag + kb + (size_t)(32 * u) * D);
      async_copy16(bl + 2048 * u, bg + kb + (size_t)(32 * u) * D);
    }
    __syncthreads();
#pragma unroll
    for (int kk = 0; kk < 2; kk++) {
      half8 af[4], bf[4];
#pragma unroll
      for (int i = 0; i < 4; i++)
        af[i] = *(const half8*)&As[(ar0 + 16 * i + c) * 64 + ((32 * kk + 8 * g) ^ cswz)];
#pragma unroll
      for (int j = 0; j < 4; j++)
        bf[j] = *(const half8*)&Bs[(bc0 + 16 * j + c) * 64 + ((32 * kk + 8 * g) ^ cswz)];
#pragma unroll
      for (int i = 0; i < 4; i++)
#pragma unroll
        for (int j = 0; j < 4; j++) acc[i][j] = MFMA_F16(af[i], bf[j], acc[i][j]);
    }
    __syncthreads();
  }

#pragma unroll
  for (int j = 0; j < 4; j++) {
    int n = col0 + bc0 + 16 * j + c;
    float bb = bias[n];   // out_b stays fp32 in the reference
#pragma unroll
    for (int i = 0; i < 4; i++) {
#pragma unroll
      for (int r = 0; r < 4; r++) {
        int m = row0 + ar0 + 16 * i + 4 * g + r;
        Out[(size_t)m * D + n] = acc[i][j][r] + bb;
      }
    }
  }
}

// ---------------------------------------------------------------------------
extern "C" void kernel_launch(void* const* d_in, const int* in_sizes, int n_in,
                              void* d_out, int out_size, void* d_ws, size_t ws_size,
                              hipStream_t stream) {
  const float* queries   = (const float*)d_in[0];
  const float* keys      = (const float*)d_in[1];
  const float* values    = (const float*)d_in[2];
  const float* m_k       = (const float*)d_in[3];
  const float* m_v       = (const float*)d_in[4];
  const float* attn_mask = (const float*)d_in[5];
  const float* in_proj_w = (const float*)d_in[6];
  const float* in_proj_b = (const float*)d_in[7];
  const float* out_w     = (const float*)d_in[8];
  const float* out_b     = (const float*)d_in[9];
  float* out = (float*)d_out;

  const size_t NA = (size_t)8192 * 1024;
  _Float16* A16  = (_Float16*)d_ws;            // 3*NA  (q16,k16,v16 contiguous)
  _Float16* Win16  = A16 + 3 * NA;             // 3*1024*1024
  _Float16* Wout16 = Win16 + (size_t)3 * 1024 * 1024;  // 1024*1024
  _Float16* Qw = Wout16 + (size_t)1024 * 1024;          // 8*16*1024*64
  _Float16* Kw = Qw + (size_t)8 * 16 * 1024 * 64;       // 8*16*1040*64
  _Float16* Vw = Kw + (size_t)8 * 16 * 1040 * 64;       // 8*16*1040*64
  _Float16* Hw = Vw + (size_t)8 * 16 * 1040 * 64;       // 8192*1024

  hipLaunchKernelGGL(convert_all, dim3(14336), dim3(256), 0, stream,
                     queries, keys, values, in_proj_w, out_w,
                     A16, A16 + NA, A16 + 2 * NA, Win16, Wout16);
  hipLaunchKernelGGL(gemm_qkv, dim3(64, 8, 3), dim3(256), 0, stream,
                     A16, Win16, in_proj_b, Qw, Kw, Vw);
  hipLaunchKernelGGL(fill_slots, dim3(1024), dim3(256), 0, stream, m_k, m_v, Kw, Vw);
  hipLaunchKernelGGL(attn, dim3(8, 128), dim3(512), 0, stream, Qw, Kw, Vw, attn_mask, Hw);
  hipLaunchKernelGGL(gemm_out, dim3(64, 8), dim3(256), 0, stream, Hw, Wout16, out_b, out);
}